// Round 13
// baseline (582.132 us; speedup 1.0000x reference)
//
#include <hip/hip_runtime.h>

typedef unsigned short u16;
typedef u16 u16x8 __attribute__((ext_vector_type(8)));
typedef float f32x4v __attribute__((ext_vector_type(4)));
typedef __bf16 bf16x8 __attribute__((ext_vector_type(8)));

// ---------- helpers ----------
__device__ __forceinline__ u16 f2bf(float f) {
  unsigned u = __builtin_bit_cast(unsigned, f);
  u += 0x7fffu + ((u >> 16) & 1u);  // round-to-nearest-even
  return (u16)(u >> 16);
}
__device__ __forceinline__ float bf2f(u16 b) {
  return __builtin_bit_cast(float, (unsigned)b << 16);
}

// ---------- fp32 -> bf16 conversion ----------
__global__ __launch_bounds__(256) void cvt_f32_bf16(const float* __restrict__ in,
                                                    u16* __restrict__ out, long n) {
  long i0 = ((long)blockIdx.x * 256 + threadIdx.x) * 8;
  long stride = (long)gridDim.x * 256 * 8;
  for (long i = i0; i < n; i += stride) {
    float4 a = *(const float4*)(in + i);
    float4 b = *(const float4*)(in + i + 4);
    u16x8 o;
    o[0] = f2bf(a.x); o[1] = f2bf(a.y); o[2] = f2bf(a.z); o[3] = f2bf(a.w);
    o[4] = f2bf(b.x); o[5] = f2bf(b.y); o[6] = f2bf(b.z); o[7] = f2bf(b.w);
    *(u16x8*)(out + i) = o;
  }
}

// ---------- 128x256 GEMM, 8-phase window with COUNTED-LGKM READ-AHEAD ----------
// Mechanism (R12 analysis): lgkmcnt(0) before every MFMA serialized ~4.6k cyc/window of
// LDS drain. Here phase i pre-issues phase i+1's ds_reads into ALTERNATE frag register
// sets and waits a COUNTED lgkm post-barrier -> next phase's LDS drain overlaps MFMA.
// Geometry: BM=128 BN=256 BK=64; 8 waves (wr 0..1 x wc 0..3), wave tile 64x64,
// acc[4][4] (64 regs) -> frag double-buffers fit the 256-reg budget.
// LDS 96KiB (u16): A half (d,h) at (d*2+h)*4096 ([64r][64k], 1 gload);
//   B half at 16384+(d*2+h)*8192 ([128r][64k], 2 gloads). Swizzle chunk c^(row&7).
// Window w = tiles t0=2w(d0), t1=2w+1(d1); 4 quadrant phases/tile (rh,ch):
//   (0,0)(0,1)(1,1)(1,0); 8 MFMA each.
// Read-ahead sets: afX(rh0) afY(rh1); bq0E/bq0O (ch0, by tile parity); bq1 (ch1).
// Per-phase pre-reads: p1:bq1(d0)4 p2:afY(d0)4 p3:0 p4:afX(d1)4+bq0O(d1)4
//   p5:bq1(d1)4 p6:afY(d1)4 p7:0 p8(nx):afX(t2)4+bq0E(t2)4.
// Post-bar counted lgkm = count just issued (DS-only -> in-order -> valid).
// Stages: p1:t1.A0 p2:t1.A1 p3:t2.B0 p4:t2.B1 p5:t2.A0 p6:t2.A1 p7:t3.B0 p8:t3.B1.
// vmcnt(2) at p3 (guards t1.* for p4-pre reads; leaves t2.B0) and p7 (guards t2.*;
// leaves t3.B0); single class (gload_lds only) -> FIFO-exact. Tail: vmcnt(0).
// Slot-overwrite hazards audited: every slot's last ds_read completes (counted lgkm)
// >=1 barrier before the stage that rewrites it.
template <int EPI>
__global__ __launch_bounds__(512, 2) void gemmRA(
    const u16* __restrict__ A, long lda, long bsA,
    const u16* __restrict__ B, long ldb, long bsB,
    void* __restrict__ Cv, long ldc, long bsC, int K,
    const int* __restrict__ maskp, float scale,
    const float* __restrict__ bias, float* __restrict__ aux) {
  extern __shared__ u16 sm[];
  const int t = threadIdx.x;
  const int lane = t & 63;
  const int w8 = t >> 6;
  const int wr = w8 >> 2;  // 0..1 : 64-row group
  const int wc = w8 & 3;   // 0..3 : 64-col group

  // T1: bijective XCD-chunked remap (all grids have nwg % 8 == 0)
  const int nwg = gridDim.x * gridDim.y * gridDim.z;
  int flat = blockIdx.x + gridDim.x * (blockIdx.y + gridDim.y * blockIdx.z);
  int nid = (flat & 7) * (nwg >> 3) + (flat >> 3);
  const int bx = nid % gridDim.x;
  const int by = (nid / gridDim.x) % gridDim.y;
  const int bz = nid / (gridDim.x * gridDim.y);

  // staging sources: thread t covers row sr of a half (B also sr+64), chunk (t&7)^(sr&7)
  const int sr = t >> 3;
  const int sc = ((t & 7) ^ (sr & 7)) * 8;
  const u16* gA_ = A + (long)bz * bsA + ((long)bx * 128 + sr) * lda + sc;
  const u16* gB_ = B + (long)bz * bsB + ((long)by * 256 + sr) * ldb + sc;

#define GLDS(gptr, lidx)                                                        \
  __builtin_amdgcn_global_load_lds(                                             \
      (const __attribute__((address_space(1))) void*)(gptr),                    \
      (__attribute__((address_space(3))) void*)(sm + (lidx)), 16, 0, 0)

#define STGA(d, h, kt)                                                          \
  GLDS(gA_ + (long)((h)*64) * lda + (long)(kt)*64, ((d)*2 + (h)) * 4096 + t * 8)
#define STGB(d, h, kt)                                                          \
  do {                                                                          \
    const int bb_ = 16384 + ((d)*2 + (h)) * 8192;                               \
    const long ko_ = (long)(kt)*64;                                             \
    GLDS(gB_ + (long)((h)*128) * ldb + ko_, bb_ + t * 8);                       \
    GLDS(gB_ + (long)((h)*128 + 64) * ldb + ko_, bb_ + 4096 + t * 8);           \
  } while (0)

  f32x4v acc[4][4];
#pragma unroll
  for (int i = 0; i < 4; ++i)
#pragma unroll
    for (int j = 0; j < 4; ++j) acc[i][j] = (f32x4v){0.f, 0.f, 0.f, 0.f};

  // frag read offsets: row r => r&7 == lane&7 for all frag rows (16/32/64 multiples)
  const int g = lane >> 4;
  const int s3 = lane & 7;
  const int rl = lane & 15;
  const int ox0 = (g ^ s3) * 8;
  const int ox1 = ((4 + g) ^ s3) * 8;
  const int aoff = rl * 64;
  const int boff = (wc & 1) * 4096 + rl * 64;

  bf16x8 afX[2][2], afY[2][2], bq0E[2][2], bq0O[2][2], bq1[2][2];

#define RDA(SET, d, rh)                                                         \
  do {                                                                          \
    const int ab_ = ((d)*2 + wr) * 4096 + (rh)*2048 + aoff;                     \
    SET[0][0] = *(const bf16x8*)(sm + ab_ + ox0);                               \
    SET[0][1] = *(const bf16x8*)(sm + ab_ + ox1);                               \
    SET[1][0] = *(const bf16x8*)(sm + ab_ + 1024 + ox0);                        \
    SET[1][1] = *(const bf16x8*)(sm + ab_ + 1024 + ox1);                        \
  } while (0)
#define RDB(SET, d, ch)                                                         \
  do {                                                                          \
    const int bb_ = 16384 + ((d)*2 + (wc >> 1)) * 8192 + (ch)*2048 + boff;      \
    SET[0][0] = *(const bf16x8*)(sm + bb_ + ox0);                               \
    SET[0][1] = *(const bf16x8*)(sm + bb_ + ox1);                               \
    SET[1][0] = *(const bf16x8*)(sm + bb_ + 1024 + ox0);                        \
    SET[1][1] = *(const bf16x8*)(sm + bb_ + 1024 + ox1);                        \
  } while (0)
#define MF(rh, ch, AF, BQ)                                                      \
  do {                                                                          \
    __builtin_amdgcn_s_setprio(1);                                              \
    _Pragma("unroll") for (int j = 0; j < 2; ++j)                               \
        _Pragma("unroll") for (int i = 0; i < 2; ++i) {                         \
      acc[(rh)*2 + j][(ch)*2 + i] = __builtin_amdgcn_mfma_f32_16x16x32_bf16(    \
          AF[j][0], BQ[i][0], acc[(rh)*2 + j][(ch)*2 + i], 0, 0, 0);            \
      acc[(rh)*2 + j][(ch)*2 + i] = __builtin_amdgcn_mfma_f32_16x16x32_bf16(    \
          AF[j][1], BQ[i][1], acc[(rh)*2 + j][(ch)*2 + i], 0, 0, 0);            \
    }                                                                           \
    __builtin_amdgcn_s_setprio(0);                                              \
  } while (0)

#define BAR __builtin_amdgcn_s_barrier()
#define LGKM(n)                                                                 \
  asm volatile("s_waitcnt lgkmcnt(" #n ")" ::: "memory");                       \
  __builtin_amdgcn_sched_barrier(0)
#define VM(n) asm volatile("s_waitcnt vmcnt(" #n ")" ::: "memory")

  const int nw = K >> 7;  // windows of 2 K-tiles

  // ---- prologue: t0.B(4), t0.A(2), t1.B(4); vmcnt(4) -> t0 landed; pre-read p1 ----
  STGB(0, 0, 0); STGB(0, 1, 0);
  STGA(0, 0, 0); STGA(0, 1, 0);
  STGB(1, 0, 1); STGB(1, 1, 1);
  VM(4);
  BAR;
  RDA(afX, 0, 0);
  RDB(bq0E, 0, 0);

  for (int w = 0; w < nw; ++w) {
    const int kt1 = 2 * w + 1;
    const bool nx = (w + 1 < nw);
    // p1: q(0,0)@t0 ; pre: bq1<-ch1(d0), stage t1.A0
    RDB(bq1, 0, 1);
    STGA(1, 0, kt1);
    BAR;
    LGKM(4);
    MF(0, 0, afX, bq0E);
    BAR;
    // p2: q(0,1)@t0 ; pre: afY<-rh1(d0), stage t1.A1
    RDA(afY, 0, 1);
    STGA(1, 1, kt1);
    BAR;
    LGKM(4);
    MF(0, 1, afX, bq1);
    BAR;
    // p3: q(1,1)@t0 ; stage t2.B0 ; vmcnt guards t1.*
    if (nx) STGB(0, 0, kt1 + 1);
    BAR;
    LGKM(0);
    MF(1, 1, afY, bq1);
    if (nx) VM(2); else VM(0);
    BAR;
    // p4: q(1,0)@t0 ; pre: afX<-rh0(d1), bq0O<-ch0(d1), stage t2.B1
    RDA(afX, 1, 0);
    RDB(bq0O, 1, 0);
    if (nx) STGB(0, 1, kt1 + 1);
    BAR;
    LGKM(8);
    MF(1, 0, afY, bq0E);
    BAR;
    // p5: q(0,0)@t1 ; pre: bq1<-ch1(d1), stage t2.A0
    RDB(bq1, 1, 1);
    if (nx) STGA(0, 0, kt1 + 1);
    BAR;
    LGKM(4);
    MF(0, 0, afX, bq0O);
    BAR;
    // p6: q(0,1)@t1 ; pre: afY<-rh1(d1), stage t2.A1
    RDA(afY, 1, 1);
    if (nx) STGA(0, 1, kt1 + 1);
    BAR;
    LGKM(4);
    MF(0, 1, afX, bq1);
    BAR;
    // p7: q(1,1)@t1 ; stage t3.B0 ; vmcnt guards t2.*
    if (nx) STGB(1, 0, kt1 + 2);
    BAR;
    LGKM(0);
    MF(1, 1, afY, bq1);
    if (nx) VM(2); else VM(0);
    BAR;
    // p8: q(1,0)@t1 ; pre(nx): afX<-rh0(t2), bq0E<-ch0(t2), stage t3.B1
    if (nx) {
      RDA(afX, 0, 0);
      RDB(bq0E, 0, 0);
      STGB(1, 1, kt1 + 2);
    }
    BAR;
    if (nx) { LGKM(8); } else { LGKM(0); }
    MF(1, 0, afY, bq0O);
    BAR;
  }
#undef STGA
#undef STGB
#undef GLDS

  // ---- epilogue: C/D layout col = lane&15, row = (lane>>4)*4 + reg ----
  const long row0 = (long)bx * 128 + wr * 64;
  const long col0 = (long)by * 256 + wc * 64;
  const int l4 = lane >> 4;
  const int cl = lane & 15;
  if constexpr (EPI == 0) {
    u16* C = (u16*)Cv + (long)bz * bsC;
    const int* mrow = maskp + (long)bz * 2048;
    int mk4[4];
#pragma unroll
    for (int fc = 0; fc < 4; ++fc) mk4[fc] = mrow[col0 + fc * 16 + cl];
#pragma unroll
    for (int fr = 0; fr < 4; ++fr) {
#pragma unroll
      for (int r = 0; r < 4; ++r) {
        long row = row0 + fr * 16 + l4 * 4 + r;
        float s = 0.f;
#pragma unroll
        for (int fc = 0; fc < 4; ++fc) {
          long col = col0 + fc * 16 + cl;
          float e = mk4[fc] ? __expf(acc[fr][fc][r] * scale + 1e-13f) : 1.0f;
          u16 eb = f2bf(e);
          C[row * ldc + col] = eb;
          s += bf2f(eb);
        }
        s += __shfl_xor(s, 1);
        s += __shfl_xor(s, 2);
        s += __shfl_xor(s, 4);
        s += __shfl_xor(s, 8);
        if (cl == 0) aux[((long)bz * 2048 + row) * 32 + by * 4 + wc] = s;
      }
    }
  } else if constexpr (EPI == 1) {
    u16* C = (u16*)Cv + (long)bz * bsC;
    const float* linv = aux + (long)bz * 2048;
#pragma unroll
    for (int fr = 0; fr < 4; ++fr) {
#pragma unroll
      for (int r = 0; r < 4; ++r) {
        long row = row0 + fr * 16 + l4 * 4 + r;
        float li = linv[row];
#pragma unroll
        for (int fc = 0; fc < 4; ++fc) {
          long col = col0 + fc * 16 + cl;
          C[row * ldc + col] = f2bf(acc[fr][fc][r] * li);
        }
      }
    }
  } else {
    float* C = (float*)Cv;
#pragma unroll
    for (int fc = 0; fc < 4; ++fc) {
      long col = col0 + fc * 16 + cl;
      float bj = bias[col];
#pragma unroll
      for (int fr = 0; fr < 4; ++fr) {
        long row = row0 + fr * 16 + l4 * 4;
#pragma unroll
        for (int r = 0; r < 4; ++r) C[(row + r) * ldc + col] = acc[fr][fc][r] + bj;
      }
    }
  }
}

// ---------- per-row 1/sum of 32 partials ----------
__global__ __launch_bounds__(256) void rowsum_inv(const float* __restrict__ part,
                                                  float* __restrict__ linv) {
  int i = blockIdx.x * 256 + threadIdx.x;  // 0..32767
  const float4* p = (const float4*)(part + (long)i * 32);
  float s = 0.f;
#pragma unroll
  for (int j = 0; j < 8; ++j) {
    float4 v = p[j];
    s += (v.x + v.y) + (v.z + v.w);
  }
  linv[i] = 1.0f / s;
}

// ---------- launcher ----------
extern "C" void kernel_launch(void* const* d_in, const int* in_sizes, int n_in,
                              void* d_out, int out_size, void* d_ws, size_t ws_size,
                              hipStream_t stream) {
  const float* Q = (const float*)d_in[0];
  const float* K = (const float*)d_in[1];
  const float* V = (const float*)d_in[2];
  const int* mask = (const int*)d_in[3];
  const float* W = (const float*)d_in[4];
  const float* bias = (const float*)d_in[5];

  const long NQ = 16L * 2048 * 1024;
  u16* Qb = (u16*)d_ws;
  u16* Kb = Qb + NQ;
  u16* Vb = Kb + NQ;
  u16* Wb = Vb + NQ;
  u16* Eb = Wb + 1024L * 1024;                     // [16][2048][2048] bf16
  float* Part = (float*)(Eb + 16L * 2048 * 2048);  // [16*2048][32] f32
  float* Linv = Part + 32768L * 32;                // [16*2048] f32
  u16* R = Qb;                                     // alias: Qb dead after GEMM1

  cvt_f32_bf16<<<2048, 256, 0, stream>>>(Q, Qb, NQ);
  cvt_f32_bf16<<<2048, 256, 0, stream>>>(K, Kb, NQ);
  cvt_f32_bf16<<<2048, 256, 0, stream>>>(V, Vb, NQ);
  cvt_f32_bf16<<<512, 256, 0, stream>>>(W, Wb, 1024L * 1024);

  // E = exp(QK^T*scale+1e-13) (masked cols -> 1.0), bf16 + per-row partial sums
  gemmRA<0><<<dim3(16, 8, 16), 512, 98304, stream>>>(
      Qb, 1024, 2048L * 1024, Kb, 1024, 2048L * 1024,
      Eb, 2048, 2048L * 2048, 1024, mask, 0.03125f, nullptr, Part);

  rowsum_inv<<<128, 256, 0, stream>>>(Part, Linv);

  // R = (E V^T) * Linv[row], bf16
  gemmRA<1><<<dim3(16, 4, 16), 512, 98304, stream>>>(
      Eb, 2048, 2048L * 2048, Vb, 2048, 1024L * 2048,
      R, 1024, 2048L * 1024, 2048, nullptr, 1.f, nullptr, Linv);

  // out = R W^T + bias
  gemmRA<2><<<dim3(256, 4, 1), 512, 98304, stream>>>(
      R, 1024, 0, Wb, 1024, 0,
      d_out, 1024, 0, 1024, nullptr, 1.f, bias, nullptr);
}

// Round 14
// 488.726 us; speedup vs baseline: 1.1911x; 1.1911x over previous
//
#include <hip/hip_runtime.h>

typedef unsigned short u16;
typedef u16 u16x8 __attribute__((ext_vector_type(8)));
typedef float f32x4v __attribute__((ext_vector_type(4)));
typedef __bf16 bf16x8 __attribute__((ext_vector_type(8)));

// ---------- helpers ----------
__device__ __forceinline__ u16 f2bf(float f) {
  unsigned u = __builtin_bit_cast(unsigned, f);
  u += 0x7fffu + ((u >> 16) & 1u);  // round-to-nearest-even
  return (u16)(u >> 16);
}
__device__ __forceinline__ float bf2f(u16 b) {
  return __builtin_bit_cast(float, (unsigned)b << 16);
}

// ---------- fp32 -> bf16 conversion ----------
__global__ __launch_bounds__(256) void cvt_f32_bf16(const float* __restrict__ in,
                                                    u16* __restrict__ out, long n) {
  long i0 = ((long)blockIdx.x * 256 + threadIdx.x) * 8;
  long stride = (long)gridDim.x * 256 * 8;
  for (long i = i0; i < n; i += stride) {
    float4 a = *(const float4*)(in + i);
    float4 b = *(const float4*)(in + i + 4);
    u16x8 o;
    o[0] = f2bf(a.x); o[1] = f2bf(a.y); o[2] = f2bf(a.z); o[3] = f2bf(a.w);
    o[4] = f2bf(b.x); o[5] = f2bf(b.y); o[6] = f2bf(b.z); o[7] = f2bf(b.w);
    *(u16x8*)(out + i) = o;
  }
}

// ---------- 256x256 GEMM, 8-phase window, ONE barrier per phase ----------
// Phase = { RD(this phase frags) ; STG(2 gloads per schedule) ; [VM] ; BAR ;
//           LGKM0+sched_barrier ; 16 MFMA }.
// Waves run ahead past MFMA into next phase's RD/STG (no post-MFMA barrier) ->
// cross-wave skew overlaps LDS drain with MFMA.
// Stage schedule (slot <- tile): p1:B(d1,h1)<-t1 p2:A(d1,h0)<-t1 p3:A(d1,h1)<-t1
//   p4:B(d0,h0)<-t2 p5:B(d0,h1)<-t2 p6:A(d0,h0)<-t2 p7:A(d0,h1)<-t2 p8:B(d1,h0)<-t3.
// WAR-safe: each stage >= lastread+2 phases with a barrier+retire chain between
//   (B(d0) read p2 -> p4; A(d0) p3 -> p6; B(d1) p6 -> p8; A(d1) p7 -> p2').
// RAW: vmcnt(2) before BAR at p4 (t1 fully landed) and p8 (t2 landed); FIFO-exact
//   (uniform 2-load stages, single op class). Tails: VM(0) / skip; p1-p3 unconditional.
// Prologue: t0.{B0,B1,A0,A1} + t1.B0 (10 loads), VM(2) -> t0 landed.
template <int EPI>
__global__ __launch_bounds__(512, 2) void gemm256(
    const u16* __restrict__ A, long lda, long bsA,
    const u16* __restrict__ B, long ldb, long bsB,
    void* __restrict__ Cv, long ldc, long bsC, int K,
    const int* __restrict__ maskp, float scale,
    const float* __restrict__ bias, float* __restrict__ aux) {
  extern __shared__ u16 sm[];
  const int t = threadIdx.x;
  const int lane = t & 63;
  const int w8 = t >> 6;
  const int wr = w8 >> 2;  // 0..1
  const int wc = w8 & 3;   // 0..3

  // T1: bijective XCD-chunked remap (all grids here have nwg % 8 == 0)
  const int nwg = gridDim.x * gridDim.y * gridDim.z;
  int flat = blockIdx.x + gridDim.x * (blockIdx.y + gridDim.y * blockIdx.z);
  int nid = (flat & 7) * (nwg >> 3) + (flat >> 3);
  const int bx = nid % gridDim.x;
  const int by = (nid / gridDim.x) % gridDim.y;
  const int bz = nid / (gridDim.x * gridDim.y);

  // staging sources: thread t covers row sr (and sr+64) of a half, chunk (t&7)^(sr&7)
  const int sr = t >> 3;
  const int sc = ((t & 7) ^ (sr & 7)) * 8;
  const u16* gA_ = A + (long)bz * bsA + ((long)bx * 256 + sr) * lda + sc;
  const u16* gB_ = B + (long)bz * bsB + ((long)by * 256 + sr) * ldb + sc;

#define GLDS(gptr, lidx)                                                        \
  __builtin_amdgcn_global_load_lds(                                             \
      (const __attribute__((address_space(1))) void*)(gptr),                    \
      (__attribute__((address_space(3))) void*)(sm + (lidx)), 16, 0, 0)

#define STG_A(d, h, kt)                                                         \
  do {                                                                          \
    const int bb = ((d)*2 + (h)) * 8192;                                        \
    const long ko = (long)(kt)*64;                                              \
    GLDS(gA_ + (long)((h)*128) * lda + ko, bb + t * 8);                         \
    GLDS(gA_ + (long)((h)*128 + 64) * lda + ko, bb + 4096 + t * 8);             \
  } while (0)
#define STG_B(d, h, kt)                                                         \
  do {                                                                          \
    const int bb = 32768 + ((d)*2 + (h)) * 8192;                                \
    const long ko = (long)(kt)*64;                                              \
    GLDS(gB_ + (long)((h)*128) * ldb + ko, bb + t * 8);                         \
    GLDS(gB_ + (long)((h)*128 + 64) * ldb + ko, bb + 4096 + t * 8);             \
  } while (0)

  f32x4v acc[8][4];
#pragma unroll
  for (int i = 0; i < 8; ++i)
#pragma unroll
    for (int j = 0; j < 4; ++j) acc[i][j] = (f32x4v){0.f, 0.f, 0.f, 0.f};

  // frag read offsets (u16): row lr, k-chunk c, phys = c ^ (lr&7)
  const int g = lane >> 4;
  const int s3 = lane & 7;
  const int rl = lane & 15;
  const int ox0 = ((0 * 4 + g) ^ s3) * 8;
  const int ox1 = ((1 * 4 + g) ^ s3) * 8;
  const int oa0 = rl * 64 + ox0, oa1 = rl * 64 + ox1;
  const int obb = (wc & 1) * 4096 + rl * 64;

  bf16x8 af[4][2], bq[4][2];

#define RD_A(d, rh)                                                             \
  do {                                                                          \
    const int ab = ((d)*2 + wr) * 8192 + (rh)*4096;                             \
    _Pragma("unroll") for (int j = 0; j < 4; ++j) {                             \
      af[j][0] = *(const bf16x8*)(sm + ab + j * 1024 + oa0);                    \
      af[j][1] = *(const bf16x8*)(sm + ab + j * 1024 + oa1);                    \
    }                                                                           \
  } while (0)
#define RD_B(d, ch)                                                             \
  do {                                                                          \
    const int bb = 32768 + ((d)*2 + (wc >> 1)) * 8192 + obb;                    \
    _Pragma("unroll") for (int i = 0; i < 2; ++i) {                             \
      bq[(ch)*2 + i][0] = *(const bf16x8*)(sm + bb + ((ch)*2 + i) * 1024 + ox0);\
      bq[(ch)*2 + i][1] = *(const bf16x8*)(sm + bb + ((ch)*2 + i) * 1024 + ox1);\
    }                                                                           \
  } while (0)
#define DO_MFMA(rh, ch)                                                         \
  do {                                                                          \
    __builtin_amdgcn_s_setprio(1);                                              \
    _Pragma("unroll") for (int j = 0; j < 4; ++j)                               \
        _Pragma("unroll") for (int i = 0; i < 2; ++i) {                         \
      acc[(rh)*4 + j][(ch)*2 + i] = __builtin_amdgcn_mfma_f32_16x16x32_bf16(    \
          af[j][0], bq[(ch)*2 + i][0], acc[(rh)*4 + j][(ch)*2 + i], 0, 0, 0);   \
      acc[(rh)*4 + j][(ch)*2 + i] = __builtin_amdgcn_mfma_f32_16x16x32_bf16(    \
          af[j][1], bq[(ch)*2 + i][1], acc[(rh)*4 + j][(ch)*2 + i], 0, 0, 0);   \
    }                                                                           \
    __builtin_amdgcn_s_setprio(0);                                              \
  } while (0)

#define BAR __builtin_amdgcn_s_barrier()
#define LGKM0                                                                   \
  asm volatile("s_waitcnt lgkmcnt(0)" ::: "memory");                            \
  __builtin_amdgcn_sched_barrier(0)
#define VM(n) asm volatile("s_waitcnt vmcnt(" #n ")" ::: "memory")

  const int nw = K >> 7;  // windows of 2 K-tiles

  // ---- prologue: t0 all (8) + t1.B0 (2); VM(2) -> t0 landed ----
  STG_B(0, 0, 0); STG_B(0, 1, 0);
  STG_A(0, 0, 0); STG_A(0, 1, 0);
  STG_B(1, 0, 1);
  VM(2);
  BAR;

  for (int w = 0; w < nw; ++w) {
    const int kt1 = 2 * w + 1;
    const bool nx = (w + 1 < nw);
    // p1: t0 q(0,0) ; stage t1.B1
    RD_A(0, 0); RD_B(0, 0);
    STG_B(1, 1, kt1);
    BAR; LGKM0;
    DO_MFMA(0, 0);
    // p2: t0 q(0,1) ; stage t1.A0
    RD_B(0, 1);
    STG_A(1, 0, kt1);
    BAR; LGKM0;
    DO_MFMA(0, 1);
    // p3: t0 q(1,1) ; stage t1.A1
    RD_A(0, 1);
    STG_A(1, 1, kt1);
    BAR; LGKM0;
    DO_MFMA(1, 1);
    // p4: t0 q(1,0) ; stage t2.B0 ; VM -> t1 landed
    if (nx) STG_B(0, 0, kt1 + 1);
    if (nx) VM(2); else VM(0);
    BAR; LGKM0;
    DO_MFMA(1, 0);
    // p5: t1 q(0,0) ; stage t2.B1
    RD_A(1, 0); RD_B(1, 0);
    if (nx) STG_B(0, 1, kt1 + 1);
    BAR; LGKM0;
    DO_MFMA(0, 0);
    // p6: t1 q(0,1) ; stage t2.A0
    RD_B(1, 1);
    if (nx) STG_A(0, 0, kt1 + 1);
    BAR; LGKM0;
    DO_MFMA(0, 1);
    // p7: t1 q(1,1) ; stage t2.A1
    RD_A(1, 1);
    if (nx) STG_A(0, 1, kt1 + 1);
    BAR; LGKM0;
    DO_MFMA(1, 1);
    // p8: t1 q(1,0) ; stage t3.B0 ; VM -> t2 landed
    if (nx) {
      STG_B(1, 0, kt1 + 2);
      VM(2);
    }
    BAR; LGKM0;
    DO_MFMA(1, 0);
  }
#undef STG_A
#undef STG_B
#undef GLDS

  // ---- epilogue: C/D layout col = lane&15, row = (lane>>4)*4 + reg ----
  const long row0 = (long)bx * 256 + wr * 128;
  const long col0 = (long)by * 256 + wc * 64;
  const int l4 = lane >> 4;
  const int cl = lane & 15;
  if constexpr (EPI == 0) {
    u16* C = (u16*)Cv + (long)bz * bsC;
    const int* mrow = maskp + (long)bz * 2048;
    int mk4[4];
#pragma unroll
    for (int fc = 0; fc < 4; ++fc) mk4[fc] = mrow[col0 + fc * 16 + cl];
#pragma unroll
    for (int fr = 0; fr < 8; ++fr) {
#pragma unroll
      for (int r = 0; r < 4; ++r) {
        long row = row0 + fr * 16 + l4 * 4 + r;
        float s = 0.f;
#pragma unroll
        for (int fc = 0; fc < 4; ++fc) {
          long col = col0 + fc * 16 + cl;
          float e = mk4[fc] ? __expf(acc[fr][fc][r] * scale + 1e-13f) : 1.0f;
          u16 eb = f2bf(e);
          C[row * ldc + col] = eb;
          s += bf2f(eb);
        }
        s += __shfl_xor(s, 1);
        s += __shfl_xor(s, 2);
        s += __shfl_xor(s, 4);
        s += __shfl_xor(s, 8);
        if (cl == 0) aux[((long)bz * 2048 + row) * 32 + by * 4 + wc] = s;
      }
    }
  } else if constexpr (EPI == 1) {
    u16* C = (u16*)Cv + (long)bz * bsC;
    const float* linv = aux + (long)bz * 2048;
#pragma unroll
    for (int fr = 0; fr < 8; ++fr) {
#pragma unroll
      for (int r = 0; r < 4; ++r) {
        long row = row0 + fr * 16 + l4 * 4 + r;
        float li = linv[row];
#pragma unroll
        for (int fc = 0; fc < 4; ++fc) {
          long col = col0 + fc * 16 + cl;
          C[row * ldc + col] = f2bf(acc[fr][fc][r] * li);
        }
      }
    }
  } else {
    float* C = (float*)Cv;
#pragma unroll
    for (int fc = 0; fc < 4; ++fc) {
      long col = col0 + fc * 16 + cl;
      float bj = bias[col];
#pragma unroll
      for (int fr = 0; fr < 8; ++fr) {
        long row = row0 + fr * 16 + l4 * 4;
#pragma unroll
        for (int r = 0; r < 4; ++r) C[(row + r) * ldc + col] = acc[fr][fc][r] + bj;
      }
    }
  }
}

// ---------- per-row 1/sum of 32 partials ----------
__global__ __launch_bounds__(256) void rowsum_inv(const float* __restrict__ part,
                                                  float* __restrict__ linv) {
  int i = blockIdx.x * 256 + threadIdx.x;  // 0..32767
  const float4* p = (const float4*)(part + (long)i * 32);
  float s = 0.f;
#pragma unroll
  for (int j = 0; j < 8; ++j) {
    float4 v = p[j];
    s += (v.x + v.y) + (v.z + v.w);
  }
  linv[i] = 1.0f / s;
}

// ---------- launcher ----------
extern "C" void kernel_launch(void* const* d_in, const int* in_sizes, int n_in,
                              void* d_out, int out_size, void* d_ws, size_t ws_size,
                              hipStream_t stream) {
  const float* Q = (const float*)d_in[0];
  const float* K = (const float*)d_in[1];
  const float* V = (const float*)d_in[2];
  const int* mask = (const int*)d_in[3];
  const float* W = (const float*)d_in[4];
  const float* bias = (const float*)d_in[5];

  const long NQ = 16L * 2048 * 1024;
  u16* Qb = (u16*)d_ws;
  u16* Kb = Qb + NQ;
  u16* Vb = Kb + NQ;
  u16* Wb = Vb + NQ;
  u16* Eb = Wb + 1024L * 1024;                     // [16][2048][2048] bf16
  float* Part = (float*)(Eb + 16L * 2048 * 2048);  // [16*2048][32] f32
  float* Linv = Part + 32768L * 32;                // [16*2048] f32
  u16* R = Qb;                                     // alias: Qb dead after GEMM1

  cvt_f32_bf16<<<2048, 256, 0, stream>>>(Q, Qb, NQ);
  cvt_f32_bf16<<<2048, 256, 0, stream>>>(K, Kb, NQ);
  cvt_f32_bf16<<<2048, 256, 0, stream>>>(V, Vb, NQ);
  cvt_f32_bf16<<<512, 256, 0, stream>>>(W, Wb, 1024L * 1024);

  // E = exp(QK^T*scale+1e-13) (masked cols -> 1.0), bf16 + per-row partial sums
  gemm256<0><<<dim3(8, 8, 16), 512, 131072, stream>>>(
      Qb, 1024, 2048L * 1024, Kb, 1024, 2048L * 1024,
      Eb, 2048, 2048L * 2048, 1024, mask, 0.03125f, nullptr, Part);

  rowsum_inv<<<128, 256, 0, stream>>>(Part, Linv);

  // R = (E V^T) * Linv[row], bf16
  gemm256<1><<<dim3(8, 4, 16), 512, 131072, stream>>>(
      Eb, 2048, 2048L * 2048, Vb, 2048, 1024L * 2048,
      R, 1024, 2048L * 1024, 2048, nullptr, 1.f, nullptr, Linv);

  // out = R W^T + bias
  gemm256<2><<<dim3(128, 4, 1), 512, 131072, stream>>>(
      R, 1024, 0, Wb, 1024, 0,
      d_out, 1024, 0, 1024, nullptr, 1.f, bias, nullptr);
}